// Round 1
// baseline (1805.069 us; speedup 1.0000x reference)
//
#include <hip/hip_runtime.h>

#define B_    64
#define NV_   6890
#define NF_   13776
#define NHD_  20000
#define NP_   24

// ---------------- workspace layout (bytes) ----------------
// zeroed zone (atomically accumulated):
#define OFF_PPV   0u           // ppv [B][NP] f32          6144
#define OFF_H     6144u        // h   [NHD][B] f32         5,120,000
#define OFF_SPW   5126144u     // sum_pw [B] f32           256
#define OFF_DCOM  5126400u     // d_com  [B] f32           256
#define OFF_RED   5126656u     // red [B][4] f32           1024  (copx,copz,comx,comz)
#define ZERO_BYTES 5127680u
// non-zeroed (fully overwritten each launch):
#define OFF_VY    5127680u     // Vy [NV][B] f32           1,763,840
#define OFF_PW    6891520u     // pw [NHD][B] f32          5,120,000
#define OFF_WV    12011520u    // wv [NHD][B] f32          5,120,000
// total = 17,131,520 bytes

// ---------------- K0: pack Vy[m][b] = vertices[b][m][1] ----------------
__global__ __launch_bounds__(256) void k0_pack(const float* __restrict__ verts,
                                               float* __restrict__ Vy) {
    int t = blockIdx.x * 256 + threadIdx.x;
    if (t >= NV_ * B_) return;
    int m = t >> 6, b = t & 63;
    Vy[t] = verts[((size_t)b * NV_ + m) * 3 + 1];
}

// ---------------- K1: per-part volumes ----------------
__global__ __launch_bounds__(256) void k1_vol(const float* __restrict__ verts,
                                              const int* __restrict__ faces,
                                              const int* __restrict__ face_part,
                                              float* __restrict__ ppv) {
    __shared__ float bins[NP_];
    int b = blockIdx.y;
    int f = blockIdx.x * 256 + threadIdx.x;
    if (threadIdx.x < NP_) bins[threadIdx.x] = 0.f;
    __syncthreads();
    if (f < NF_) {
        int i0 = faces[3 * f], i1 = faces[3 * f + 1], i2 = faces[3 * f + 2];
        const float* vb = verts + (size_t)b * NV_ * 3;
        float ax = vb[3 * i0], ay = vb[3 * i0 + 1], az = vb[3 * i0 + 2];
        float bx = vb[3 * i1], by = vb[3 * i1 + 1], bz = vb[3 * i1 + 2];
        float cx = vb[3 * i2], cy = vb[3 * i2 + 1], cz = vb[3 * i2 + 2];
        float crx = by * cz - bz * cy;
        float cry = bz * cx - bx * cz;
        float crz = bx * cy - by * cx;
        float vol = fabsf(ax * crx + ay * cry + az * crz) * (1.0f / 6.0f);
        atomicAdd(&bins[face_part[f]], vol);
    }
    __syncthreads();
    if (threadIdx.x < NP_) atomicAdd(&ppv[b * NP_ + threadIdx.x], bins[threadIdx.x]);
}

// ---------------- K2a: h[n][b] = sum_k H[n][k] * Vy[k][b] ----------------
// tile: 256 n x 64 b, KB=16, 256 thr, micro 8x8, split-k = 8 via atomics
#define K2A_KB 16
__global__ __launch_bounds__(256, 2) void k2a_h(const float* __restrict__ Hm,
                                                const float* __restrict__ Vy,
                                                float* __restrict__ h) {
    __shared__ float As[K2A_KB][260];   // [k][n] transposed, pad to 260
    __shared__ float Bs[K2A_KB][64];    // [k][b]
    int nb = blockIdx.x;                // 0..78
    int s  = blockIdx.y;                // 0..7
    int tid = threadIdx.x;
    int tn = tid >> 3;                  // 0..31 (n dim)
    int tb = tid & 7;                   // 0..7  (b dim)
    int n0 = nb * 256;
    int c0 = s * 54;
    int c1 = c0 + 54; if (c1 > 431) c1 = 431;   // 431 chunks of 16 cover K=6890
    float acc[8][8] = {};
    for (int c = c0; c < c1; ++c) {
        int k0 = c * 16;
        // H tile: 256 rows x 16 k via float2 (row stride 6890 breaks f4 align)
        #pragma unroll
        for (int i = 0; i < 8; ++i) {
            int idx = i * 256 + tid;
            int r  = idx >> 3;          // n-local 0..255
            int kk = (idx & 7) * 2;     // 0..14 even
            int n = n0 + r, k = k0 + kk;
            float2 v = make_float2(0.f, 0.f);
            if (n < NHD_ && k + 1 < NV_)
                v = *reinterpret_cast<const float2*>(Hm + (size_t)n * NV_ + k);
            As[kk][r]     = v.x;
            As[kk + 1][r] = v.y;
        }
        {   // Vy tile: 16 x 64, float4
            int r = tid >> 4, b4 = (tid & 15) * 4;
            int k = k0 + r;
            float4 v = make_float4(0.f, 0.f, 0.f, 0.f);
            if (k < NV_) v = *reinterpret_cast<const float4*>(Vy + (size_t)k * 64 + b4);
            *reinterpret_cast<float4*>(&Bs[r][b4]) = v;
        }
        __syncthreads();
        #pragma unroll
        for (int kk = 0; kk < K2A_KB; ++kk) {
            float4 a0 = *reinterpret_cast<const float4*>(&As[kk][tn * 8]);
            float4 a1 = *reinterpret_cast<const float4*>(&As[kk][tn * 8 + 4]);
            float4 b0 = *reinterpret_cast<const float4*>(&Bs[kk][tb * 8]);
            float4 b1 = *reinterpret_cast<const float4*>(&Bs[kk][tb * 8 + 4]);
            float a[8] = {a0.x, a0.y, a0.z, a0.w, a1.x, a1.y, a1.z, a1.w};
            float bv[8] = {b0.x, b0.y, b0.z, b0.w, b1.x, b1.y, b1.z, b1.w};
            #pragma unroll
            for (int i = 0; i < 8; ++i)
                #pragma unroll
                for (int j = 0; j < 8; ++j)
                    acc[i][j] = fmaf(a[i], bv[j], acc[i][j]);
        }
        __syncthreads();
    }
    #pragma unroll
    for (int i = 0; i < 8; ++i) {
        int n = n0 + tn * 8 + i;
        if (n < NHD_) {
            #pragma unroll
            for (int j = 0; j < 8; ++j)
                atomicAdd(&h[n * 64 + tb * 8 + j], acc[i][j]);
        }
    }
}

// ---------------- K2b: pw, wv, sum_pw, d_com ----------------
__global__ __launch_bounds__(256) void k2b_pwwv(const float* __restrict__ h,
                                                const int* __restrict__ vert_fid,
                                                const int* __restrict__ face_part,
                                                const float* __restrict__ ppv,
                                                float* __restrict__ pw,
                                                float* __restrict__ wv,
                                                float* __restrict__ sum_pw,
                                                float* __restrict__ d_com) {
    __shared__ float red2[2][256];
    int b  = threadIdx.x & 63;
    int nl = threadIdx.x >> 6;          // 0..3
    int base = blockIdx.x * 64;
    float sp = 0.f, sw = 0.f;
    for (int r = 0; r < 16; ++r) {
        int n = base + nl * 16 + r;
        if (n < NHD_) {
            float hv = h[n * 64 + b];
            float p = (hv < 0.f) ? (1.f - 100.0f * hv) : expf(-10.0f * hv);
            int part = face_part[vert_fid[n]];
            float w = ppv[b * NP_ + part];
            pw[n * 64 + b] = p;
            wv[n * 64 + b] = w;
            sp += p; sw += w;
        }
    }
    red2[0][threadIdx.x] = sp;
    red2[1][threadIdx.x] = sw;
    __syncthreads();
    if (threadIdx.x < 64) {
        float s0 = red2[0][threadIdx.x] + red2[0][threadIdx.x + 64] +
                   red2[0][threadIdx.x + 128] + red2[0][threadIdx.x + 192];
        float s1 = red2[1][threadIdx.x] + red2[1][threadIdx.x + 64] +
                   red2[1][threadIdx.x + 128] + red2[1][threadIdx.x + 192];
        atomicAdd(&sum_pw[threadIdx.x], s0);
        atomicAdd(&d_com[threadIdx.x], s1);
    }
}

// ---------------- K4: A_cop/A_com GEMM + fused contraction with V(x,z) ----------------
// tile: 64 b x 256 m, k(=n) chunks of 32, 256 thr, micro 8b x 8m, n-split 25
#define K4_KB 32
__global__ __launch_bounds__(256, 2) void k4_gemm2(const float* __restrict__ Hm,
                                                   const float* __restrict__ pw,
                                                   const float* __restrict__ wv,
                                                   const float* __restrict__ verts,
                                                   float* __restrict__ red) {
    __shared__ float Hs[K4_KB][260];    // [n][m] pad
    __shared__ float Ps[K4_KB][64];     // pw [n][b]
    __shared__ float Ws[K4_KB][64];     // wv [n][b]
    __shared__ float Rs[64][4];
    int mb = blockIdx.x;                // 0..26
    int s  = blockIdx.y;                // 0..24
    int tid = threadIdx.x;
    int tm = tid >> 3;                  // 0..31 (m dim)
    int tb = tid & 7;                   // 0..7  (b dim)
    int m0 = mb * 256;
    int c0 = s * 25, c1 = c0 + 25;      // 25*25 = 625 chunks of 32 = 20000 exact
    float ac[8][8] = {};                // cop acc [b][m]
    float am[8][8] = {};                // com acc [b][m]
    for (int c = c0; c < c1; ++c) {
        int n0 = c * 32;
        #pragma unroll
        for (int i = 0; i < 16; ++i) {  // H tile: 32 n x 256 m via float2
            int idx = i * 256 + tid;
            int r  = idx >> 7;          // 0..31
            int mm = (idx & 127) * 2;   // 0..254
            int m = m0 + mm;
            float2 v = make_float2(0.f, 0.f);
            if (m + 1 < NV_)
                v = *reinterpret_cast<const float2*>(Hm + (size_t)(n0 + r) * NV_ + m);
            *reinterpret_cast<float2*>(&Hs[r][mm]) = v;
        }
        #pragma unroll
        for (int i = 0; i < 2; ++i) {   // pw/wv tiles: 32 x 64, float4
            int idx = i * 256 + tid;
            int r = idx >> 4, b4 = (idx & 15) * 4;
            size_t off = (size_t)(n0 + r) * 64 + b4;
            *reinterpret_cast<float4*>(&Ps[r][b4]) = *reinterpret_cast<const float4*>(pw + off);
            *reinterpret_cast<float4*>(&Ws[r][b4]) = *reinterpret_cast<const float4*>(wv + off);
        }
        __syncthreads();
        #pragma unroll
        for (int kk = 0; kk < K4_KB; ++kk) {
            float4 p0 = *reinterpret_cast<const float4*>(&Ps[kk][tb * 8]);
            float4 p1 = *reinterpret_cast<const float4*>(&Ps[kk][tb * 8 + 4]);
            float4 w0 = *reinterpret_cast<const float4*>(&Ws[kk][tb * 8]);
            float4 w1 = *reinterpret_cast<const float4*>(&Ws[kk][tb * 8 + 4]);
            float4 h0 = *reinterpret_cast<const float4*>(&Hs[kk][tm * 8]);
            float4 h1 = *reinterpret_cast<const float4*>(&Hs[kk][tm * 8 + 4]);
            float pv[8] = {p0.x, p0.y, p0.z, p0.w, p1.x, p1.y, p1.z, p1.w};
            float wvv[8] = {w0.x, w0.y, w0.z, w0.w, w1.x, w1.y, w1.z, w1.w};
            float hv[8] = {h0.x, h0.y, h0.z, h0.w, h1.x, h1.y, h1.z, h1.w};
            #pragma unroll
            for (int i = 0; i < 8; ++i)
                #pragma unroll
                for (int j = 0; j < 8; ++j) {
                    ac[i][j] = fmaf(pv[i], hv[j], ac[i][j]);
                    am[i][j] = fmaf(wvv[i], hv[j], am[i][j]);
                }
        }
        __syncthreads();
    }
    // epilogue: contract with vertices x/z, reduce per b
    float px[8] = {}, pz[8] = {}, qx[8] = {}, qz[8] = {};
    #pragma unroll
    for (int j = 0; j < 8; ++j) {
        int m = m0 + tm * 8 + j;
        if (m < NV_) {
            #pragma unroll
            for (int i = 0; i < 8; ++i) {
                int b = tb * 8 + i;
                float vx = verts[((size_t)b * NV_ + m) * 3 + 0];
                float vz = verts[((size_t)b * NV_ + m) * 3 + 2];
                px[i] += ac[i][j] * vx;
                pz[i] += ac[i][j] * vz;
                qx[i] += am[i][j] * vx;
                qz[i] += am[i][j] * vz;
            }
        }
    }
    if (tid < 64) { Rs[tid][0] = 0.f; Rs[tid][1] = 0.f; Rs[tid][2] = 0.f; Rs[tid][3] = 0.f; }
    __syncthreads();
    #pragma unroll
    for (int i = 0; i < 8; ++i) {
        int b = tb * 8 + i;
        atomicAdd(&Rs[b][0], px[i]);
        atomicAdd(&Rs[b][1], pz[i]);
        atomicAdd(&Rs[b][2], qx[i]);
        atomicAdd(&Rs[b][3], qz[i]);
    }
    __syncthreads();
    if (tid < 64) {
        atomicAdd(&red[tid * 4 + 0], Rs[tid][0]);
        atomicAdd(&red[tid * 4 + 1], Rs[tid][1]);
        atomicAdd(&red[tid * 4 + 2], Rs[tid][2]);
        atomicAdd(&red[tid * 4 + 3], Rs[tid][3]);
    }
}

// ---------------- K5: finalize ----------------
__global__ __launch_bounds__(64) void k5_final(const float* __restrict__ red,
                                               const float* __restrict__ sum_pw,
                                               const float* __restrict__ d_com,
                                               float* __restrict__ out) {
    int b = threadIdx.x;
    if (b < B_) {
        float spw = sum_pw[b] + 1e-6f;
        float copx = red[b * 4 + 0] / spw;
        float copz = red[b * 4 + 1] / spw;
        float comx = red[b * 4 + 2] / d_com[b];
        float comz = red[b * 4 + 3] / d_com[b];
        float dx = comx - copx, dz = comz - copz;
        out[b] = sqrtf(dx * dx + dz * dz);
    }
}

extern "C" void kernel_launch(void* const* d_in, const int* in_sizes, int n_in,
                              void* d_out, int out_size, void* d_ws, size_t ws_size,
                              hipStream_t stream) {
    const float* verts     = (const float*)d_in[0];
    const float* Hm        = (const float*)d_in[1];
    const int*   faces     = (const int*)d_in[2];
    const int*   vert_fid  = (const int*)d_in[3];
    const int*   face_part = (const int*)d_in[4];
    char* ws = (char*)d_ws;
    float* ppv = (float*)(ws + OFF_PPV);
    float* h   = (float*)(ws + OFF_H);
    float* spw = (float*)(ws + OFF_SPW);
    float* dcm = (float*)(ws + OFF_DCOM);
    float* red = (float*)(ws + OFF_RED);
    float* Vy  = (float*)(ws + OFF_VY);
    float* pw  = (float*)(ws + OFF_PW);
    float* wv  = (float*)(ws + OFF_WV);
    float* out = (float*)d_out;

    hipMemsetAsync(d_ws, 0, ZERO_BYTES, stream);
    hipLaunchKernelGGL(k0_pack, dim3((NV_ * B_ + 255) / 256), dim3(256), 0, stream, verts, Vy);
    hipLaunchKernelGGL(k1_vol, dim3(54, 64), dim3(256), 0, stream, verts, faces, face_part, ppv);
    hipLaunchKernelGGL(k2a_h, dim3(79, 8), dim3(256), 0, stream, Hm, Vy, h);
    hipLaunchKernelGGL(k2b_pwwv, dim3(313), dim3(256), 0, stream,
                       h, vert_fid, face_part, ppv, pw, wv, spw, dcm);
    hipLaunchKernelGGL(k4_gemm2, dim3(27, 25), dim3(256), 0, stream, Hm, pw, wv, verts, red);
    hipLaunchKernelGGL(k5_final, dim3(1), dim3(64), 0, stream, red, spw, dcm, out);
}

// Round 2
// 456.381 us; speedup vs baseline: 3.9552x; 3.9552x over previous
//
#include <hip/hip_runtime.h>
#include <cstdint>

#define B_    64
#define NV_   6890
#define NF_   13776
#define NHD_  20000
#define NP_   24
#define KPAD  6912          // NV_ padded to 32-chunk multiple, zeros in pad
#define NCH   216           // ceil(6890/32)

// ---------------- workspace layout (bytes) ----------------
#define OFF_PPV   0u        // ppv [64][24] f32   6144   (zeroed)
#define OFF_RED   6144u     // red [64][6]  f32   1536   (zeroed) copx,copz,comx,comz,sp,sw
#define ZERO_BYTES 7680u
#define OFF_VT    7680u     // Vt  [192][6912] bf16  2,654,208  (fully rewritten)
// total ~2.66 MB

typedef __attribute__((ext_vector_type(8))) __bf16 bf16x8;
typedef __attribute__((ext_vector_type(8))) unsigned short u16x8;
typedef __attribute__((ext_vector_type(4))) float f32x4;

__device__ __forceinline__ unsigned short f2bf(float f) {
    unsigned u = __float_as_uint(f);
    u = (u + 0x7fffu + ((u >> 16) & 1u)) >> 16;   // RNE (no NaN inputs here)
    return (unsigned short)u;
}

// ---------------- K0v: pack V_T[bd][m] bf16, bd = d*64+b, zero-pad m>=NV ----------------
__global__ __launch_bounds__(256) void k0v_pack(const float* __restrict__ verts,
                                                unsigned short* __restrict__ Vt) {
    int t = blockIdx.x * 256 + threadIdx.x;
    if (t >= 192 * KPAD) return;
    int c = t / KPAD, m = t - c * KPAD;
    int d = c >> 6, b = c & 63;
    float v = (m < NV_) ? verts[((size_t)b * NV_ + m) * 3 + d] : 0.f;
    Vt[t] = f2bf(v);
}

// ---------------- K1: per-part volumes (unchanged, verified) ----------------
__global__ __launch_bounds__(256) void k1_vol(const float* __restrict__ verts,
                                              const int* __restrict__ faces,
                                              const int* __restrict__ face_part,
                                              float* __restrict__ ppv) {
    __shared__ float bins[NP_];
    int b = blockIdx.y;
    int f = blockIdx.x * 256 + threadIdx.x;
    if (threadIdx.x < NP_) bins[threadIdx.x] = 0.f;
    __syncthreads();
    if (f < NF_) {
        int i0 = faces[3 * f], i1 = faces[3 * f + 1], i2 = faces[3 * f + 2];
        const float* vb = verts + (size_t)b * NV_ * 3;
        float ax = vb[3 * i0], ay = vb[3 * i0 + 1], az = vb[3 * i0 + 2];
        float bx = vb[3 * i1], by = vb[3 * i1 + 1], bz = vb[3 * i1 + 2];
        float cx = vb[3 * i2], cy = vb[3 * i2 + 1], cz = vb[3 * i2 + 2];
        float crx = by * cz - bz * cy;
        float cry = bz * cx - bx * cz;
        float crz = bx * cy - by * cx;
        float vol = fabsf(ax * crx + ay * cry + az * crz) * (1.0f / 6.0f);
        atomicAdd(&bins[face_part[f]], vol);
    }
    __syncthreads();
    if (threadIdx.x < NP_) atomicAdd(&ppv[b * NP_ + threadIdx.x], bins[threadIdx.x]);
}

// ---------------- KF: fused  vhd = H x V (bf16 MFMA)  ->  pw/wv weight -> reduce ----------
// block = 128 thr = 2 waves; wave owns 16 rows x 192 cols (12 MFMA tiles of 16x16x32).
// B-frags: tiles 0..5 via LDS staging (double-buffered), tiles 6..11 direct from L2.
__global__ __launch_bounds__(128) void kf_fused(const float* __restrict__ Hm,
                                                const unsigned short* __restrict__ Vt,
                                                const int* __restrict__ vert_fid,
                                                const int* __restrict__ face_part,
                                                const float* __restrict__ ppv,
                                                float* __restrict__ red) {
    __shared__ unsigned short Vl[2][96 * 32];   // staged bd rows 0..95, 32 k, dbuf (12 KB)
    __shared__ float reds[B_ * 6];
    const int tid  = threadIdx.x;
    const int lane = tid & 63;
    const int wv   = tid >> 6;
    const int lm   = lane & 15;          // A row / B col / C col within tile
    const int kg   = lane >> 4;          // k-group (8 elems each)
    const int n0   = blockIdx.x * 32 + wv * 16;
    const float* Arow = Hm + (size_t)(n0 + lm) * NV_ + kg * 8;

    // ---- prologue: stage V chunk 0, prefetch A chunk 0
    uint4 vreg[3];
#pragma unroll
    for (int j = 0; j < 3; ++j) {
        int L = j * 128 + tid;           // L>>2 = bd row 0..95, L&3 = 8-elem segment
        vreg[j] = *reinterpret_cast<const uint4*>(Vt + (size_t)(L >> 2) * KPAD + (L & 3) * 8);
    }
#pragma unroll
    for (int j = 0; j < 3; ++j)
        *reinterpret_cast<uint4*>(&Vl[0][(j * 128 + tid) * 8]) = vreg[j];

    float2 a0 = *reinterpret_cast<const float2*>(Arow + 0);
    float2 a1 = *reinterpret_cast<const float2*>(Arow + 2);
    float2 a2 = *reinterpret_cast<const float2*>(Arow + 4);
    float2 a3 = *reinterpret_cast<const float2*>(Arow + 6);

    f32x4 acc[12];
#pragma unroll
    for (int t = 0; t < 12; ++t) acc[t] = (f32x4){0.f, 0.f, 0.f, 0.f};

    __syncthreads();
    int p = 0;
    for (int c = 0; c < NCH; ++c) {
        // convert prefetched A (8 f32 -> bf16x8 frag)
        u16x8 au;
        au[0] = f2bf(a0.x); au[1] = f2bf(a0.y); au[2] = f2bf(a1.x); au[3] = f2bf(a1.y);
        au[4] = f2bf(a2.x); au[5] = f2bf(a2.y); au[6] = f2bf(a3.x); au[7] = f2bf(a3.y);
        bf16x8 Af = __builtin_bit_cast(bf16x8, au);

        // ---- prefetch next chunk (A rows from HBM, staged-V rows from L2)
        if (c + 1 < NCH) {
            const int k0n = (c + 1) * 32;
            if (c + 1 == NCH - 1) {      // partial tail chunk: guarded loads
                float tf[8];
#pragma unroll
                for (int j = 0; j < 8; ++j) {
                    int k = k0n + kg * 8 + j;
                    tf[j] = (k < NV_) ? Hm[(size_t)(n0 + lm) * NV_ + k] : 0.f;
                }
                a0 = make_float2(tf[0], tf[1]); a1 = make_float2(tf[2], tf[3]);
                a2 = make_float2(tf[4], tf[5]); a3 = make_float2(tf[6], tf[7]);
            } else {
                a0 = *reinterpret_cast<const float2*>(Arow + k0n);
                a1 = *reinterpret_cast<const float2*>(Arow + k0n + 2);
                a2 = *reinterpret_cast<const float2*>(Arow + k0n + 4);
                a3 = *reinterpret_cast<const float2*>(Arow + k0n + 6);
            }
#pragma unroll
            for (int j = 0; j < 3; ++j) {
                int L = j * 128 + tid;
                vreg[j] = *reinterpret_cast<const uint4*>(
                    Vt + (size_t)(L >> 2) * KPAD + k0n + (L & 3) * 8);
            }
        }

        const int k0 = c * 32;
        // direct-L2 B frags, tiles 6..11 (bd 96..191)
        bf16x8 Bg[6];
#pragma unroll
        for (int i = 0; i < 6; ++i) {
            const unsigned short* bp = Vt + (size_t)(16 * (6 + i) + lm) * KPAD + k0 + kg * 8;
            Bg[i] = __builtin_bit_cast(bf16x8, *reinterpret_cast<const u16x8*>(bp));
        }
        // LDS B frags, tiles 0..5
        const unsigned short* Vb = &Vl[p][0];
#pragma unroll
        for (int i = 0; i < 6; ++i) {
            bf16x8 Bl = *reinterpret_cast<const bf16x8*>(Vb + (16 * i + lm) * 32 + kg * 8);
            acc[i] = __builtin_amdgcn_mfma_f32_16x16x32_bf16(Af, Bl, acc[i], 0, 0, 0);
        }
#pragma unroll
        for (int i = 0; i < 6; ++i)
            acc[6 + i] = __builtin_amdgcn_mfma_f32_16x16x32_bf16(Af, Bg[i], acc[6 + i], 0, 0, 0);

        // write staged V for next chunk into other buffer; one barrier per iter
        if (c + 1 < NCH) {
#pragma unroll
            for (int j = 0; j < 3; ++j)
                *reinterpret_cast<uint4*>(&Vl[p ^ 1][(j * 128 + tid) * 8]) = vreg[j];
        }
        __syncthreads();
        p ^= 1;
    }

    // ---- epilogue: pw from y-plane (tiles 4..7), weight x/z planes, reduce
    for (int i = tid; i < B_ * 6; i += 128) reds[i] = 0.f;
    __syncthreads();

    int prt[4];
#pragma unroll
    for (int r = 0; r < 4; ++r) prt[r] = face_part[vert_fid[n0 + kg * 4 + r]];

#pragma unroll
    for (int t = 0; t < 4; ++t) {
        int b = t * 16 + lm;
        float scx = 0.f, scz = 0.f, smx = 0.f, smz = 0.f, ssp = 0.f, ssw = 0.f;
#pragma unroll
        for (int r = 0; r < 4; ++r) {
            float x = acc[t][r];
            float h = acc[4 + t][r];
            float z = acc[8 + t][r];
            float pwv = (h < 0.f) ? (1.f - 100.f * h) : expf(-10.f * h);
            float w = ppv[b * NP_ + prt[r]];
            scx += pwv * x; scz += pwv * z;
            smx += w * x;   smz += w * z;
            ssp += pwv;     ssw += w;
        }
        atomicAdd(&reds[b * 6 + 0], scx);
        atomicAdd(&reds[b * 6 + 1], scz);
        atomicAdd(&reds[b * 6 + 2], smx);
        atomicAdd(&reds[b * 6 + 3], smz);
        atomicAdd(&reds[b * 6 + 4], ssp);
        atomicAdd(&reds[b * 6 + 5], ssw);
    }
    __syncthreads();
    for (int i = tid; i < B_ * 6; i += 128) atomicAdd(&red[i], reds[i]);
}

// ---------------- K5: finalize ----------------
__global__ __launch_bounds__(64) void k5_final(const float* __restrict__ red,
                                               float* __restrict__ out) {
    int b = threadIdx.x;
    if (b < B_) {
        float sp   = red[b * 6 + 4] + 1e-6f;
        float sw   = red[b * 6 + 5];
        float copx = red[b * 6 + 0] / sp;
        float copz = red[b * 6 + 1] / sp;
        float comx = red[b * 6 + 2] / sw;
        float comz = red[b * 6 + 3] / sw;
        float dx = comx - copx, dz = comz - copz;
        out[b] = sqrtf(dx * dx + dz * dz);
    }
}

extern "C" void kernel_launch(void* const* d_in, const int* in_sizes, int n_in,
                              void* d_out, int out_size, void* d_ws, size_t ws_size,
                              hipStream_t stream) {
    const float* verts     = (const float*)d_in[0];
    const float* Hm        = (const float*)d_in[1];
    const int*   faces     = (const int*)d_in[2];
    const int*   vert_fid  = (const int*)d_in[3];
    const int*   face_part = (const int*)d_in[4];
    char* ws = (char*)d_ws;
    float*          ppv = (float*)(ws + OFF_PPV);
    float*          red = (float*)(ws + OFF_RED);
    unsigned short* Vt  = (unsigned short*)(ws + OFF_VT);
    float* out = (float*)d_out;

    hipMemsetAsync(d_ws, 0, ZERO_BYTES, stream);
    hipLaunchKernelGGL(k0v_pack, dim3((192 * KPAD) / 256), dim3(256), 0, stream, verts, Vt);
    hipLaunchKernelGGL(k1_vol, dim3(54, 64), dim3(256), 0, stream, verts, faces, face_part, ppv);
    hipLaunchKernelGGL(kf_fused, dim3(NHD_ / 32), dim3(128), 0, stream,
                       Hm, Vt, vert_fid, face_part, ppv, red);
    hipLaunchKernelGGL(k5_final, dim3(1), dim3(64), 0, stream, red, out);
}

// Round 3
// 312.577 us; speedup vs baseline: 5.7748x; 1.4601x over previous
//
#include <hip/hip_runtime.h>
#include <cstdint>

#define B_    64
#define NV_   6890
#define NF_   13776
#define NHD_  20000
#define NP_   24
#define NCH   216           // ceil(6890/32) k-chunks of 32
#define KSPL  4             // split-K across waves in a block
#define CPW   54            // chunks per wave (216/4)

// ---------------- workspace layout (bytes) ----------------
#define OFF_PPV   0u        // ppv [64][24] f32   6144   (zeroed)
#define OFF_RED   6144u     // red [64][6]  f32   1536   (zeroed)
#define ZERO_BYTES 7680u
#define OFF_VC    7680u     // Vc [216][12][64][8] bf16 = 2,654,208 B (fully rewritten)

typedef __attribute__((ext_vector_type(8))) __bf16 bf16x8;
typedef __attribute__((ext_vector_type(8))) unsigned short u16x8;
typedef __attribute__((ext_vector_type(4))) float f32x4;

__device__ __forceinline__ unsigned short f2bf(float f) {
    unsigned u = __float_as_uint(f);
    u = (u + 0x7fffu + ((u >> 16) & 1u)) >> 16;   // RNE (no NaNs here)
    return (unsigned short)u;
}

// ---------------- K0v: pack V into MFMA-fragment order ----------------
// Vc[((c*12 + t)*64 + lane)*8 + j] = V_bf16[bd = t*16 + (lane&15)][k = c*32 + (lane>>4)*8 + j]
// where V[bd][k] = verts[b= bd&63][m=k][d= bd>>6], zero-padded for k >= NV_.
__global__ __launch_bounds__(256) void k0v_pack(const float* __restrict__ verts,
                                                unsigned short* __restrict__ Vc) {
    int idx = blockIdx.x * 256 + threadIdx.x;       // 216*12*512 = 1,327,104 total
    int j    = idx & 7;
    int lane = (idx >> 3) & 63;
    int ct   = idx >> 9;                            // c*12 + t
    int t    = ct % 12;
    int c    = ct / 12;
    int lm   = lane & 15;
    int kk   = (lane >> 4) * 8 + j;
    int bd   = t * 16 + lm;
    int d    = bd >> 6, b = bd & 63;
    int k    = c * 32 + kk;
    float v  = (k < NV_) ? verts[((size_t)b * NV_ + k) * 3 + d] : 0.f;
    Vc[idx] = f2bf(v);
}

// ---------------- K1: per-part volumes ----------------
__global__ __launch_bounds__(256) void k1_vol(const float* __restrict__ verts,
                                              const int* __restrict__ faces,
                                              const int* __restrict__ face_part,
                                              float* __restrict__ ppv) {
    __shared__ float bins[NP_];
    int b = blockIdx.y;
    int f = blockIdx.x * 256 + threadIdx.x;
    if (threadIdx.x < NP_) bins[threadIdx.x] = 0.f;
    __syncthreads();
    if (f < NF_) {
        int i0 = faces[3 * f], i1 = faces[3 * f + 1], i2 = faces[3 * f + 2];
        const float* vb = verts + (size_t)b * NV_ * 3;
        float ax = vb[3 * i0], ay = vb[3 * i0 + 1], az = vb[3 * i0 + 2];
        float bx = vb[3 * i1], by = vb[3 * i1 + 1], bz = vb[3 * i1 + 2];
        float cx = vb[3 * i2], cy = vb[3 * i2 + 1], cz = vb[3 * i2 + 2];
        float crx = by * cz - bz * cy;
        float cry = bz * cx - bx * cz;
        float crz = bx * cy - by * cx;
        float vol = fabsf(ax * crx + ay * cry + az * crz) * (1.0f / 6.0f);
        atomicAdd(&bins[face_part[f]], vol);
    }
    __syncthreads();
    if (threadIdx.x < NP_) atomicAdd(&ppv[b * NP_ + threadIdx.x], bins[threadIdx.x]);
}

// ---------------- KF: barrier-free fused GEMM + weight + reduce ----------------
// block = 256 thr = 4 waves, all on rows n0..n0+15; wave s does chunks [54s, 54s+54).
// Main loop: NO barriers, NO LDS. B tiles are 1KB coalesced L2 reads in frag order.
__global__ __launch_bounds__(256, 3) void kf_fused(const float* __restrict__ Hm,
                                                   const unsigned short* __restrict__ Vc,
                                                   const int* __restrict__ vert_fid,
                                                   const int* __restrict__ face_part,
                                                   const float* __restrict__ ppv,
                                                   float* __restrict__ red) {
    __shared__ float accs[16 * 192];    // full-sum C tile [row][bd]
    __shared__ float reds[B_ * 6];
    const int tid  = threadIdx.x;
    const int lane = tid & 63;
    const int s    = tid >> 6;          // wave id = K-split id
    const int lm   = lane & 15;
    const int kg   = lane >> 4;
    const int n0   = blockIdx.x * 16;
    const float* Arow = Hm + (size_t)(n0 + lm) * NV_;

    const int cs = s * CPW, ce = cs + CPW;

    f32x4 acc[12];
#pragma unroll
    for (int t = 0; t < 12; ++t) acc[t] = (f32x4){0.f, 0.f, 0.f, 0.f};

    float2 a0, a1, a2, a3, na0, na1, na2, na3;

    auto issueA = [&](int c, float2& b0, float2& b1, float2& b2, float2& b3) {
        int k0 = c * 32 + kg * 8;
        if (c == NCH - 1) {             // tail chunk: guarded scalar loads
            float tf[8];
#pragma unroll
            for (int j = 0; j < 8; ++j) {
                int k = k0 + j;
                tf[j] = (k < NV_) ? Arow[k] : 0.f;
            }
            b0 = make_float2(tf[0], tf[1]); b1 = make_float2(tf[2], tf[3]);
            b2 = make_float2(tf[4], tf[5]); b3 = make_float2(tf[6], tf[7]);
        } else {
            b0 = *reinterpret_cast<const float2*>(Arow + k0);
            b1 = *reinterpret_cast<const float2*>(Arow + k0 + 2);
            b2 = *reinterpret_cast<const float2*>(Arow + k0 + 4);
            b3 = *reinterpret_cast<const float2*>(Arow + k0 + 6);
        }
    };

    issueA(cs, a0, a1, a2, a3);
    for (int c = cs; c < ce; ++c) {
        // 12 B-tile fragment loads: 1KB coalesced each, from L2-resident Vc
        const u16x8* Bp = reinterpret_cast<const u16x8*>(Vc) + (size_t)c * 12 * 64 + lane;
        u16x8 Bu[12];
#pragma unroll
        for (int t = 0; t < 12; ++t) Bu[t] = Bp[t * 64];
        // prefetch next A chunk (HBM) before computing on current
        if (c + 1 < ce) issueA(c + 1, na0, na1, na2, na3);
        // convert A to bf16 frag
        u16x8 au;
        au[0] = f2bf(a0.x); au[1] = f2bf(a0.y); au[2] = f2bf(a1.x); au[3] = f2bf(a1.y);
        au[4] = f2bf(a2.x); au[5] = f2bf(a2.y); au[6] = f2bf(a3.x); au[7] = f2bf(a3.y);
        bf16x8 Af = __builtin_bit_cast(bf16x8, au);
#pragma unroll
        for (int t = 0; t < 12; ++t)
            acc[t] = __builtin_amdgcn_mfma_f32_16x16x32_bf16(
                Af, __builtin_bit_cast(bf16x8, Bu[t]), acc[t], 0, 0, 0);
        a0 = na0; a1 = na1; a2 = na2; a3 = na3;
    }

    // ---- split-K reduction in LDS ----
    for (int i = tid; i < 16 * 192; i += 256) accs[i] = 0.f;
    for (int i = tid; i < B_ * 6; i += 256) reds[i] = 0.f;
    __syncthreads();
    // acc[t][r] = C[row = kg*4 + r][bd = t*16 + lm]   (verified mapping)
#pragma unroll
    for (int t = 0; t < 12; ++t)
#pragma unroll
        for (int r = 0; r < 4; ++r)
            atomicAdd(&accs[(kg * 4 + r) * 192 + t * 16 + lm], acc[t][r]);
    __syncthreads();

    // ---- epilogue: pw from y-plane, weight x/z, per-b reduce ----
    {
        int b  = tid & 63;
        int r0 = tid >> 6;              // 0..3
        float scx = 0.f, scz = 0.f, smx = 0.f, smz = 0.f, ssp = 0.f, ssw = 0.f;
#pragma unroll
        for (int q = 0; q < 4; ++q) {
            int row = q * 4 + r0;
            int n = n0 + row;
            float x = accs[row * 192 + b];
            float h = accs[row * 192 + 64 + b];
            float z = accs[row * 192 + 128 + b];
            float pwv = (h < 0.f) ? (1.f - 100.f * h) : expf(-10.f * h);
            int part = face_part[vert_fid[n]];
            float w = ppv[b * NP_ + part];
            scx += pwv * x; scz += pwv * z;
            smx += w * x;   smz += w * z;
            ssp += pwv;     ssw += w;
        }
        atomicAdd(&reds[b * 6 + 0], scx);
        atomicAdd(&reds[b * 6 + 1], scz);
        atomicAdd(&reds[b * 6 + 2], smx);
        atomicAdd(&reds[b * 6 + 3], smz);
        atomicAdd(&reds[b * 6 + 4], ssp);
        atomicAdd(&reds[b * 6 + 5], ssw);
    }
    __syncthreads();
    for (int i = tid; i < B_ * 6; i += 256) atomicAdd(&red[i], reds[i]);
}

// ---------------- K5: finalize ----------------
__global__ __launch_bounds__(64) void k5_final(const float* __restrict__ red,
                                               float* __restrict__ out) {
    int b = threadIdx.x;
    if (b < B_) {
        float sp   = red[b * 6 + 4] + 1e-6f;
        float sw   = red[b * 6 + 5];
        float copx = red[b * 6 + 0] / sp;
        float copz = red[b * 6 + 1] / sp;
        float comx = red[b * 6 + 2] / sw;
        float comz = red[b * 6 + 3] / sw;
        float dx = comx - copx, dz = comz - copz;
        out[b] = sqrtf(dx * dx + dz * dz);
    }
}

extern "C" void kernel_launch(void* const* d_in, const int* in_sizes, int n_in,
                              void* d_out, int out_size, void* d_ws, size_t ws_size,
                              hipStream_t stream) {
    const float* verts     = (const float*)d_in[0];
    const float* Hm        = (const float*)d_in[1];
    const int*   faces     = (const int*)d_in[2];
    const int*   vert_fid  = (const int*)d_in[3];
    const int*   face_part = (const int*)d_in[4];
    char* ws = (char*)d_ws;
    float*          ppv = (float*)(ws + OFF_PPV);
    float*          red = (float*)(ws + OFF_RED);
    unsigned short* Vc  = (unsigned short*)(ws + OFF_VC);
    float* out = (float*)d_out;

    hipMemsetAsync(d_ws, 0, ZERO_BYTES, stream);
    hipLaunchKernelGGL(k0v_pack, dim3((NCH * 12 * 512) / 256), dim3(256), 0, stream, verts, Vc);
    hipLaunchKernelGGL(k1_vol, dim3(54, 64), dim3(256), 0, stream, verts, faces, face_part, ppv);
    hipLaunchKernelGGL(kf_fused, dim3(NHD_ / 16), dim3(256), 0, stream,
                       Hm, Vc, vert_fid, face_part, ppv, red);
    hipLaunchKernelGGL(k5_final, dim3(1), dim3(64), 0, stream, red, out);
}

// Round 4
// 303.531 us; speedup vs baseline: 5.9469x; 1.0298x over previous
//
#include <hip/hip_runtime.h>
#include <cstdint>

#define B_    64
#define NV_   6890
#define NF_   13776
#define NHD_  20000
#define NP_   24
#define NCH   216           // ceil(6890/32) k-chunks of 32
#define KSPL  4             // split-K across waves in a block
#define CPW   54            // chunks per wave (216/4)

// ---------------- workspace layout (bytes) ----------------
#define OFF_PPV   0u        // ppv [64][24] f32   6144   (zeroed)
#define OFF_RED   6144u     // red [64][6]  f32   1536   (zeroed)
#define ZERO_BYTES 7680u
#define OFF_VC    7680u     // Vc [216][12][64][8] bf16 = 2,654,208 B (fully rewritten)

typedef __attribute__((ext_vector_type(8))) __bf16 bf16x8;
typedef __attribute__((ext_vector_type(8))) unsigned short u16x8;
typedef __attribute__((ext_vector_type(4))) float f32x4;

__device__ __forceinline__ unsigned short f2bf(float f) {
    unsigned u = __float_as_uint(f);
    u = (u + 0x7fffu + ((u >> 16) & 1u)) >> 16;   // RNE (no NaNs here)
    return (unsigned short)u;
}

// ---------------- K0v: pack V into MFMA-fragment order (unchanged layout) ----------------
// Vc[((c*12 + t)*64 + lane)*8 + j] = V_bf16[bd = t*16 + (lane&15)][k = c*32 + (lane>>4)*8 + j]
__global__ __launch_bounds__(256) void k0v_pack(const float* __restrict__ verts,
                                                unsigned short* __restrict__ Vc) {
    int idx = blockIdx.x * 256 + threadIdx.x;       // 216*12*512 = 1,327,104 total
    int j    = idx & 7;
    int lane = (idx >> 3) & 63;
    int ct   = idx >> 9;                            // c*12 + t
    int t    = ct % 12;
    int c    = ct / 12;
    int lm   = lane & 15;
    int kk   = (lane >> 4) * 8 + j;
    int bd   = t * 16 + lm;
    int d    = bd >> 6, b = bd & 63;
    int k    = c * 32 + kk;
    float v  = (k < NV_) ? verts[((size_t)b * NV_ + k) * 3 + d] : 0.f;
    Vc[idx] = f2bf(v);
}

// ---------------- K1: per-part volumes ----------------
__global__ __launch_bounds__(256) void k1_vol(const float* __restrict__ verts,
                                              const int* __restrict__ faces,
                                              const int* __restrict__ face_part,
                                              float* __restrict__ ppv) {
    __shared__ float bins[NP_];
    int b = blockIdx.y;
    int f = blockIdx.x * 256 + threadIdx.x;
    if (threadIdx.x < NP_) bins[threadIdx.x] = 0.f;
    __syncthreads();
    if (f < NF_) {
        int i0 = faces[3 * f], i1 = faces[3 * f + 1], i2 = faces[3 * f + 2];
        const float* vb = verts + (size_t)b * NV_ * 3;
        float ax = vb[3 * i0], ay = vb[3 * i0 + 1], az = vb[3 * i0 + 2];
        float bx = vb[3 * i1], by = vb[3 * i1 + 1], bz = vb[3 * i1 + 2];
        float cx = vb[3 * i2], cy = vb[3 * i2 + 1], cz = vb[3 * i2 + 2];
        float crx = by * cz - bz * cy;
        float cry = bz * cx - bx * cz;
        float crz = bx * cy - by * cx;
        float vol = fabsf(ax * crx + ay * cry + az * crz) * (1.0f / 6.0f);
        atomicAdd(&bins[face_part[f]], vol);
    }
    __syncthreads();
    if (threadIdx.x < NP_) atomicAdd(&ppv[b * NP_ + threadIdx.x], bins[threadIdx.x]);
}

// ---------------- KF: 32 rows/block, 4-wave split-K, barrier-free main loop ----------------
// Each wave: rows n0..n0+31 (two 16-row MFMA tiles sharing B frags), chunks [54s, 54s+54).
// Two-pass MFMA over t keeps all 12 Bu live -> compiler must issue all loads up front.
#define ACCP 193            // padded LDS stride (192 % 32 == 0 would 4-way conflict)
__global__ __launch_bounds__(256) void kf_fused(const float* __restrict__ Hm,
                                                const unsigned short* __restrict__ Vc,
                                                const int* __restrict__ vert_fid,
                                                const int* __restrict__ face_part,
                                                const float* __restrict__ ppv,
                                                float* __restrict__ red) {
    __shared__ float accs[32 * ACCP];   // 24,704 B
    __shared__ float reds[B_ * 6];
    const int tid  = threadIdx.x;
    const int lane = tid & 63;
    const int s    = tid >> 6;          // wave id = K-split id
    const int lm   = lane & 15;
    const int kg   = lane >> 4;
    const int n0   = blockIdx.x * 32;
    const float* Arow0 = Hm + (size_t)(n0 + lm) * NV_;
    const float* Arow1 = Hm + (size_t)(n0 + 16 + lm) * NV_;
    const int cs = s * CPW, ce = cs + CPW;

    f32x4 acc0[12], acc1[12];
#pragma unroll
    for (int t = 0; t < 12; ++t) {
        acc0[t] = (f32x4){0.f, 0.f, 0.f, 0.f};
        acc1[t] = (f32x4){0.f, 0.f, 0.f, 0.f};
    }

    float2 a[4], b[4], na[4], nb[4];

    auto issueA = [&](int c, const float* R, float2* dst) {
        int k0 = c * 32 + kg * 8;
        if (c == NCH - 1) {             // tail chunk: guarded scalar loads
            float tf[8];
#pragma unroll
            for (int j = 0; j < 8; ++j) {
                int k = k0 + j;
                tf[j] = (k < NV_) ? R[k] : 0.f;
            }
            dst[0] = make_float2(tf[0], tf[1]); dst[1] = make_float2(tf[2], tf[3]);
            dst[2] = make_float2(tf[4], tf[5]); dst[3] = make_float2(tf[6], tf[7]);
        } else {
            dst[0] = *reinterpret_cast<const float2*>(R + k0);
            dst[1] = *reinterpret_cast<const float2*>(R + k0 + 2);
            dst[2] = *reinterpret_cast<const float2*>(R + k0 + 4);
            dst[3] = *reinterpret_cast<const float2*>(R + k0 + 6);
        }
    };

    issueA(cs, Arow0, a);
    issueA(cs, Arow1, b);
    for (int c = cs; c < ce; ++c) {
        // 12 B-tile fragment loads, all issued before the MFMA passes (MLP=12)
        const u16x8* Bp = reinterpret_cast<const u16x8*>(Vc) + (size_t)c * 12 * 64 + lane;
        u16x8 Bu[12];
#pragma unroll
        for (int t = 0; t < 12; ++t) Bu[t] = Bp[t * 64];
        // prefetch next A chunk (HBM) before computing on current
        if (c + 1 < ce) { issueA(c + 1, Arow0, na); issueA(c + 1, Arow1, nb); }
        // convert current A rows to bf16 frags
        u16x8 au0, au1;
        au0[0] = f2bf(a[0].x); au0[1] = f2bf(a[0].y); au0[2] = f2bf(a[1].x); au0[3] = f2bf(a[1].y);
        au0[4] = f2bf(a[2].x); au0[5] = f2bf(a[2].y); au0[6] = f2bf(a[3].x); au0[7] = f2bf(a[3].y);
        au1[0] = f2bf(b[0].x); au1[1] = f2bf(b[0].y); au1[2] = f2bf(b[1].x); au1[3] = f2bf(b[1].y);
        au1[4] = f2bf(b[2].x); au1[5] = f2bf(b[2].y); au1[6] = f2bf(b[3].x); au1[7] = f2bf(b[3].y);
        bf16x8 Af0 = __builtin_bit_cast(bf16x8, au0);
        bf16x8 Af1 = __builtin_bit_cast(bf16x8, au1);
#pragma unroll
        for (int t = 0; t < 12; ++t)
            acc0[t] = __builtin_amdgcn_mfma_f32_16x16x32_bf16(
                Af0, __builtin_bit_cast(bf16x8, Bu[t]), acc0[t], 0, 0, 0);
#pragma unroll
        for (int t = 0; t < 12; ++t)
            acc1[t] = __builtin_amdgcn_mfma_f32_16x16x32_bf16(
                Af1, __builtin_bit_cast(bf16x8, Bu[t]), acc1[t], 0, 0, 0);
#pragma unroll
        for (int j = 0; j < 4; ++j) { a[j] = na[j]; b[j] = nb[j]; }
    }

    // ---- split-K reduction in LDS ----
    for (int i = tid; i < 32 * ACCP; i += 256) accs[i] = 0.f;
    for (int i = tid; i < B_ * 6; i += 256) reds[i] = 0.f;
    __syncthreads();
    // acc0[t][r] = C[row = kg*4 + r][bd = t*16 + lm], acc1 rows +16 (verified mapping)
#pragma unroll
    for (int t = 0; t < 12; ++t)
#pragma unroll
        for (int r = 0; r < 4; ++r) {
            atomicAdd(&accs[(kg * 4 + r) * ACCP + t * 16 + lm], acc0[t][r]);
            atomicAdd(&accs[(16 + kg * 4 + r) * ACCP + t * 16 + lm], acc1[t][r]);
        }
    __syncthreads();

    // ---- epilogue: pw from y-plane, weight x/z, per-b reduce ----
    {
        int bb = tid & 63;
        int r0 = tid >> 6;              // 0..3
        float scx = 0.f, scz = 0.f, smx = 0.f, smz = 0.f, ssp = 0.f, ssw = 0.f;
#pragma unroll
        for (int q = 0; q < 8; ++q) {
            int row = q * 4 + r0;       // 0..31
            int n = n0 + row;
            float x = accs[row * ACCP + bb];
            float h = accs[row * ACCP + 64 + bb];
            float z = accs[row * ACCP + 128 + bb];
            float pwv = (h < 0.f) ? (1.f - 100.f * h) : expf(-10.f * h);
            int part = face_part[vert_fid[n]];
            float w = ppv[bb * NP_ + part];
            scx += pwv * x; scz += pwv * z;
            smx += w * x;   smz += w * z;
            ssp += pwv;     ssw += w;
        }
        atomicAdd(&reds[bb * 6 + 0], scx);
        atomicAdd(&reds[bb * 6 + 1], scz);
        atomicAdd(&reds[bb * 6 + 2], smx);
        atomicAdd(&reds[bb * 6 + 3], smz);
        atomicAdd(&reds[bb * 6 + 4], ssp);
        atomicAdd(&reds[bb * 6 + 5], ssw);
    }
    __syncthreads();
    for (int i = tid; i < B_ * 6; i += 256) atomicAdd(&red[i], reds[i]);
}

// ---------------- K5: finalize ----------------
__global__ __launch_bounds__(64) void k5_final(const float* __restrict__ red,
                                               float* __restrict__ out) {
    int b = threadIdx.x;
    if (b < B_) {
        float sp   = red[b * 6 + 4] + 1e-6f;
        float sw   = red[b * 6 + 5];
        float copx = red[b * 6 + 0] / sp;
        float copz = red[b * 6 + 1] / sp;
        float comx = red[b * 6 + 2] / sw;
        float comz = red[b * 6 + 3] / sw;
        float dx = comx - copx, dz = comz - copz;
        out[b] = sqrtf(dx * dx + dz * dz);
    }
}

extern "C" void kernel_launch(void* const* d_in, const int* in_sizes, int n_in,
                              void* d_out, int out_size, void* d_ws, size_t ws_size,
                              hipStream_t stream) {
    const float* verts     = (const float*)d_in[0];
    const float* Hm        = (const float*)d_in[1];
    const int*   faces     = (const int*)d_in[2];
    const int*   vert_fid  = (const int*)d_in[3];
    const int*   face_part = (const int*)d_in[4];
    char* ws = (char*)d_ws;
    float*          ppv = (float*)(ws + OFF_PPV);
    float*          red = (float*)(ws + OFF_RED);
    unsigned short* Vc  = (unsigned short*)(ws + OFF_VC);
    float* out = (float*)d_out;

    hipMemsetAsync(d_ws, 0, ZERO_BYTES, stream);
    hipLaunchKernelGGL(k0v_pack, dim3((NCH * 12 * 512) / 256), dim3(256), 0, stream, verts, Vc);
    hipLaunchKernelGGL(k1_vol, dim3(54, 64), dim3(256), 0, stream, verts, faces, face_part, ppv);
    hipLaunchKernelGGL(kf_fused, dim3(NHD_ / 32), dim3(256), 0, stream,
                       Hm, Vc, vert_fid, face_part, ppv, red);
    hipLaunchKernelGGL(k5_final, dim3(1), dim3(64), 0, stream, red, out);
}